// Round 1
// baseline (15702.486 us; speedup 1.0000x reference)
//
#include <hip/hip_runtime.h>

#define NN 20000
#define GG 256

__device__ __forceinline__ float lrelu(float x) { return x > 0.f ? x : 0.2f * x; }

__device__ __forceinline__ void atomicMaxF(float* addr, float val) {
    // sign-aware int punning: works for mixed signs, init -inf
    if (val >= 0.f) atomicMax((int*)addr, __float_as_int(val));
    else            atomicMin((unsigned int*)addr, __float_as_uint(val));
}

// e[n,c] = emb[xi[n]*128 + c]
__global__ void k_embed(const int* __restrict__ xi, const float* __restrict__ emb,
                        float* __restrict__ e, int n) {
    int idx = blockIdx.x * blockDim.x + threadIdx.x;
    if (idx >= n * 128) return;
    int node = idx >> 7, c = idx & 127;
    e[idx] = emb[(xi[node] << 7) | c];
}

// C[n,M] = A[n,K] @ B[K,M] (+bias1[c]) (+bias2[c]); row-major; M % 64 == 0, K % 16 == 0
__global__ __launch_bounds__(256) void k_gemm(const float* __restrict__ A,
                                              const float* __restrict__ B,
                                              float* __restrict__ C,
                                              int n, int K, int M,
                                              const float* __restrict__ bias1,
                                              const float* __restrict__ bias2) {
    const int BK = 16;
    __shared__ float As[BK][65];
    __shared__ float Bs[BK][65];
    int tid = threadIdx.x;
    int tx = tid & 15, ty = tid >> 4;
    int row0 = blockIdx.x * 64;
    int col0 = blockIdx.y * 64;
    float acc[4][4] = {};
    for (int k0 = 0; k0 < K; k0 += BK) {
#pragma unroll
        for (int t = 0; t < 4; t++) {
            int i = tid + t * 256;
            int r = i >> 4, kk = i & 15;
            int gr = row0 + r;
            As[kk][r] = (gr < n) ? A[(size_t)gr * K + k0 + kk] : 0.f;
        }
#pragma unroll
        for (int t = 0; t < 4; t++) {
            int i = tid + t * 256;
            int kk = i >> 6, c = i & 63;
            Bs[kk][c] = B[(size_t)(k0 + kk) * M + col0 + c];
        }
        __syncthreads();
#pragma unroll
        for (int kk = 0; kk < BK; kk++) {
            float ra[4], rb[4];
#pragma unroll
            for (int i = 0; i < 4; i++) ra[i] = As[kk][ty * 4 + i];
#pragma unroll
            for (int j = 0; j < 4; j++) rb[j] = Bs[kk][tx * 4 + j];
#pragma unroll
            for (int i = 0; i < 4; i++)
#pragma unroll
                for (int j = 0; j < 4; j++) acc[i][j] += ra[i] * rb[j];
        }
        __syncthreads();
    }
#pragma unroll
    for (int i = 0; i < 4; i++) {
        int gr = row0 + ty * 4 + i;
        if (gr >= n) continue;
#pragma unroll
        for (int j = 0; j < 4; j++) {
            int gc = col0 + tx * 4 + j;
            float v = acc[i][j];
            if (bias1) v += bias1[gc];
            if (bias2) v += bias2[gc];
            C[(size_t)gr * M + gc] = v;
        }
    }
}

// a_s[n,h] = sum_c xh[n,h*C+c]*att_s[h*C+c]; same for a_d
template <int C>
__global__ void k_attn(const float* __restrict__ xh, const float* __restrict__ att_s,
                       const float* __restrict__ att_d, float* __restrict__ a_s,
                       float* __restrict__ a_d, int n) {
    int idx = blockIdx.x * blockDim.x + threadIdx.x;
    if (idx >= n * 4) return;
    int node = idx >> 2, h = idx & 3;
    const float* row = xh + (size_t)node * (4 * C) + h * C;
    float ss = 0.f, dd = 0.f;
#pragma unroll 4
    for (int c = 0; c < C; c++) {
        float v = row[c];
        ss += v * att_s[h * C + c];
        dd += v * att_d[h * C + c];
    }
    a_s[idx] = ss;
    a_d[idx] = dd;
}

__global__ void k_init_mz(float* __restrict__ m, float* __restrict__ z, int n4) {
    int i = blockIdx.x * blockDim.x + threadIdx.x;
    if (i < n4) { m[i] = -INFINITY; z[i] = 0.f; }
}

__global__ void k_edge_max(const int* __restrict__ edges, int E, int n,
                           const float* __restrict__ a_s, const float* __restrict__ a_d,
                           float* __restrict__ m) {
    int e = blockIdx.x * blockDim.x + threadIdx.x;
    int Et = E + n;
    if (e >= Et) return;
    int s, d;
    if (e < E) { s = edges[e]; d = edges[E + e]; } else { s = d = e - E; }
    float4 as = ((const float4*)a_s)[s];
    float4 ad = ((const float4*)a_d)[d];
    atomicMaxF(&m[d * 4 + 0], lrelu(as.x + ad.x));
    atomicMaxF(&m[d * 4 + 1], lrelu(as.y + ad.y));
    atomicMaxF(&m[d * 4 + 2], lrelu(as.z + ad.z));
    atomicMaxF(&m[d * 4 + 3], lrelu(as.w + ad.w));
}

__global__ void k_edge_expsum(const int* __restrict__ edges, int E, int n,
                              const float* __restrict__ a_s, const float* __restrict__ a_d,
                              const float* __restrict__ m, float* __restrict__ z) {
    int e = blockIdx.x * blockDim.x + threadIdx.x;
    int Et = E + n;
    if (e >= Et) return;
    int s, d;
    if (e < E) { s = edges[e]; d = edges[E + e]; } else { s = d = e - E; }
    float4 as = ((const float4*)a_s)[s];
    float4 ad = ((const float4*)a_d)[d];
    float4 mm = ((const float4*)m)[d];
    atomicAdd(&z[d * 4 + 0], expf(lrelu(as.x + ad.x) - mm.x));
    atomicAdd(&z[d * 4 + 1], expf(lrelu(as.y + ad.y) - mm.y));
    atomicAdd(&z[d * 4 + 2], expf(lrelu(as.z + ad.z) - mm.z));
    atomicAdd(&z[d * 4 + 3], expf(lrelu(as.w + ad.w) - mm.w));
}

// one wave per edge; lane covers HC/64 contiguous channels (within one head)
template <int HC, int C>
__global__ void k_edge_scatter(const int* __restrict__ edges, int E, int n,
                               const float* __restrict__ a_s, const float* __restrict__ a_d,
                               const float* __restrict__ m, const float* __restrict__ z,
                               const float* __restrict__ xh, float* __restrict__ acc) {
    int wave = (blockIdx.x * blockDim.x + threadIdx.x) >> 6;
    int lane = threadIdx.x & 63;
    int Et = E + n;
    if (wave >= Et) return;
    int e = wave;
    int s, d;
    if (e < E) { s = edges[e]; d = edges[E + e]; } else { s = d = e - E; }
    constexpr int VC = HC / 64;  // 4 or 8
    int c0 = lane * VC;
    int h = c0 / C;
    float logit = lrelu(a_s[s * 4 + h] + a_d[d * 4 + h]);
    float alpha = expf(logit - m[d * 4 + h]) / (z[d * 4 + h] + 1e-16f);
    const float* xr = xh + (size_t)s * HC + c0;
    float* ar = acc + (size_t)d * HC + c0;
#pragma unroll
    for (int j = 0; j < VC; j += 4) {
        float4 v = *((const float4*)(xr + j));
        atomicAdd(ar + j + 0, alpha * v.x);
        atomicAdd(ar + j + 1, alpha * v.y);
        atomicAdd(ar + j + 2, alpha * v.z);
        atomicAdd(ar + j + 3, alpha * v.w);
    }
}

__global__ void k_relu(float* __restrict__ x, int total) {
    int i = blockIdx.x * blockDim.x + threadIdx.x;
    if (i < total) x[i] = fmaxf(x[i], 0.f);
}

// out3[n,c] = mean_h(agg[n,h,c]) + b3[c] + lin3[n,c]; scatter into pool[batch[n],c]
__global__ void k_combine3(const float* __restrict__ agg, const float* __restrict__ lin3,
                           const float* __restrict__ b3, const int* __restrict__ batch,
                           float* __restrict__ pool, float* __restrict__ cnt, int n) {
    int idx = blockIdx.x * blockDim.x + threadIdx.x;
    if (idx >= n * 128) return;
    int node = idx >> 7, c = idx & 127;
    const float* a = agg + (size_t)node * 512;
    float v = 0.25f * (a[c] + a[128 + c] + a[256 + c] + a[384 + c]) + b3[c] + lin3[idx];
    int g = batch[node];
    atomicAdd(&pool[g * 128 + c], v);
    if (c == 0) atomicAdd(&cnt[g], 1.0f);
}

__global__ void k_div(float* __restrict__ out, const float* __restrict__ cnt, int total) {
    int idx = blockIdx.x * blockDim.x + threadIdx.x;
    if (idx >= total) return;
    int g = idx >> 7;  // matches cnt layout [2*G]
    out[idx] /= fmaxf(cnt[g], 1.0f);
}

static inline int cdiv(int a, int b) { return (a + b - 1) / b; }

extern "C" void kernel_launch(void* const* d_in, const int* in_sizes, int n_in,
                              void* d_out, int out_size, void* d_ws, size_t ws_size,
                              hipStream_t stream) {
    const int* x_l = (const int*)d_in[0];
    const int* edge_l = (const int*)d_in[1];
    const int* batch_l = (const int*)d_in[2];
    const int* x_r = (const int*)d_in[3];
    const int* edge_r = (const int*)d_in[4];
    const int* batch_r = (const int*)d_in[5];
    const float* emb = (const float*)d_in[6];
    const float* W1 = (const float*)d_in[7];
    const float* as1 = (const float*)d_in[8];
    const float* ad1 = (const float*)d_in[9];
    const float* b1 = (const float*)d_in[10];
    const float* lw1 = (const float*)d_in[11];
    const float* lb1 = (const float*)d_in[12];
    const float* W2 = (const float*)d_in[13];
    const float* as2 = (const float*)d_in[14];
    const float* ad2 = (const float*)d_in[15];
    const float* b2 = (const float*)d_in[16];
    const float* lw2 = (const float*)d_in[17];
    const float* lb2 = (const float*)d_in[18];
    const float* W3 = (const float*)d_in[19];
    const float* as3 = (const float*)d_in[20];
    const float* ad3 = (const float*)d_in[21];
    const float* b3 = (const float*)d_in[22];
    const float* lw3 = (const float*)d_in[23];
    const float* lb3 = (const float*)d_in[24];

    const int n = in_sizes[0];       // 20000
    const int E = in_sizes[1] / 2;   // 320000
    const int Et = E + n;

    float* P0 = (float*)d_ws;                 // [n,512] xh buffer
    float* P1 = P0 + (size_t)n * 512;         // [n,512] acc / agg
    float* P2 = P1 + (size_t)n * 512;         // [n,512] features
    float* L3 = P2 + (size_t)n * 512;         // [n,128] layer-3 skip
    float* a_s = L3 + (size_t)n * 128;        // [n,4]
    float* a_d = a_s + (size_t)n * 4;
    float* m_ = a_d + (size_t)n * 4;
    float* z_ = m_ + (size_t)n * 4;
    float* cnt = z_ + (size_t)n * 4;          // [2*G]

    hipMemsetAsync(d_out, 0, sizeof(float) * (size_t)out_size, stream);
    hipMemsetAsync(cnt, 0, sizeof(float) * 2 * GG, stream);

    const int TB = 256;
    dim3 blk(TB);

    for (int side = 0; side < 2; side++) {
        const int* xi = side ? x_r : x_l;
        const int* edges = side ? edge_r : edge_l;
        const int* batch = side ? batch_r : batch_l;
        float* pool = (float*)d_out + (size_t)side * GG * 128;
        float* cside = cnt + side * GG;

        // embed -> P2 [n,128]
        k_embed<<<cdiv(n * 128, TB), blk, 0, stream>>>(xi, emb, P2, n);

        // ---- layer 1 (K=128, HC=256, C=64) ----
        k_gemm<<<dim3(cdiv(n, 64), 4), blk, 0, stream>>>(P2, W1, P0, n, 128, 256, nullptr, nullptr);
        k_gemm<<<dim3(cdiv(n, 64), 4), blk, 0, stream>>>(P2, lw1, P1, n, 128, 256, lb1, b1);
        k_attn<64><<<cdiv(n * 4, TB), blk, 0, stream>>>(P0, as1, ad1, a_s, a_d, n);
        k_init_mz<<<cdiv(n * 4, TB), blk, 0, stream>>>(m_, z_, n * 4);
        k_edge_max<<<cdiv(Et, TB), blk, 0, stream>>>(edges, E, n, a_s, a_d, m_);
        k_edge_expsum<<<cdiv(Et, TB), blk, 0, stream>>>(edges, E, n, a_s, a_d, m_, z_);
        k_edge_scatter<256, 64><<<cdiv(Et * 64, TB), blk, 0, stream>>>(edges, E, n, a_s, a_d, m_, z_, P0, P1);
        k_relu<<<cdiv(n * 256, TB), blk, 0, stream>>>(P1, n * 256);

        // ---- layer 2 (K=256, HC=256, C=64) ----
        k_gemm<<<dim3(cdiv(n, 64), 4), blk, 0, stream>>>(P1, W2, P0, n, 256, 256, nullptr, nullptr);
        k_gemm<<<dim3(cdiv(n, 64), 4), blk, 0, stream>>>(P1, lw2, P2, n, 256, 256, lb2, b2);
        k_attn<64><<<cdiv(n * 4, TB), blk, 0, stream>>>(P0, as2, ad2, a_s, a_d, n);
        k_init_mz<<<cdiv(n * 4, TB), blk, 0, stream>>>(m_, z_, n * 4);
        k_edge_max<<<cdiv(Et, TB), blk, 0, stream>>>(edges, E, n, a_s, a_d, m_);
        k_edge_expsum<<<cdiv(Et, TB), blk, 0, stream>>>(edges, E, n, a_s, a_d, m_, z_);
        k_edge_scatter<256, 64><<<cdiv(Et * 64, TB), blk, 0, stream>>>(edges, E, n, a_s, a_d, m_, z_, P0, P2);
        k_relu<<<cdiv(n * 256, TB), blk, 0, stream>>>(P2, n * 256);

        // ---- layer 3 (K=256, HC=512, C=128, concat=False) ----
        k_gemm<<<dim3(cdiv(n, 64), 8), blk, 0, stream>>>(P2, W3, P0, n, 256, 512, nullptr, nullptr);
        k_gemm<<<dim3(cdiv(n, 64), 2), blk, 0, stream>>>(P2, lw3, L3, n, 256, 128, lb3, nullptr);
        k_attn<128><<<cdiv(n * 4, TB), blk, 0, stream>>>(P0, as3, ad3, a_s, a_d, n);
        k_init_mz<<<cdiv(n * 4, TB), blk, 0, stream>>>(m_, z_, n * 4);
        k_edge_max<<<cdiv(Et, TB), blk, 0, stream>>>(edges, E, n, a_s, a_d, m_);
        k_edge_expsum<<<cdiv(Et, TB), blk, 0, stream>>>(edges, E, n, a_s, a_d, m_, z_);
        hipMemsetAsync(P1, 0, sizeof(float) * (size_t)n * 512, stream);
        k_edge_scatter<512, 128><<<cdiv(Et * 64, TB), blk, 0, stream>>>(edges, E, n, a_s, a_d, m_, z_, P0, P1);
        k_combine3<<<cdiv(n * 128, TB), blk, 0, stream>>>(P1, L3, b3, batch, pool, cside, n);
    }
    k_div<<<cdiv(2 * GG * 128, TB), blk, 0, stream>>>((float*)d_out, cnt, 2 * GG * 128);
}

// Round 2
// 1680.667 us; speedup vs baseline: 9.3430x; 9.3430x over previous
//
#include <hip/hip_runtime.h>

#define GG 256

__device__ __forceinline__ float lrelu(float x) { return x > 0.f ? x : 0.2f * x; }

// e[n,c] = emb[xi[n]*128 + c]
__global__ void k_embed(const int* __restrict__ xi, const float* __restrict__ emb,
                        float* __restrict__ e, int n) {
    int idx = blockIdx.x * blockDim.x + threadIdx.x;
    if (idx >= n * 128) return;
    int node = idx >> 7, c = idx & 127;
    e[idx] = emb[(xi[node] << 7) | c];
}

// C[n,M] = A[n,K] @ B[K,M] (+bias1[c]) (+bias2[c]); row-major; M % 64 == 0, K % 16 == 0
__global__ __launch_bounds__(256) void k_gemm(const float* __restrict__ A,
                                              const float* __restrict__ B,
                                              float* __restrict__ C,
                                              int n, int K, int M,
                                              const float* __restrict__ bias1,
                                              const float* __restrict__ bias2) {
    const int BK = 16;
    __shared__ float As[BK][65];
    __shared__ float Bs[BK][65];
    int tid = threadIdx.x;
    int tx = tid & 15, ty = tid >> 4;
    int row0 = blockIdx.x * 64;
    int col0 = blockIdx.y * 64;
    float acc[4][4] = {};
    for (int k0 = 0; k0 < K; k0 += BK) {
#pragma unroll
        for (int t = 0; t < 4; t++) {
            int i = tid + t * 256;
            int r = i >> 4, kk = i & 15;
            int gr = row0 + r;
            As[kk][r] = (gr < n) ? A[(size_t)gr * K + k0 + kk] : 0.f;
        }
#pragma unroll
        for (int t = 0; t < 4; t++) {
            int i = tid + t * 256;
            int kk = i >> 6, c = i & 63;
            Bs[kk][c] = B[(size_t)(k0 + kk) * M + col0 + c];
        }
        __syncthreads();
#pragma unroll
        for (int kk = 0; kk < BK; kk++) {
            float ra[4], rb[4];
#pragma unroll
            for (int i = 0; i < 4; i++) ra[i] = As[kk][ty * 4 + i];
#pragma unroll
            for (int j = 0; j < 4; j++) rb[j] = Bs[kk][tx * 4 + j];
#pragma unroll
            for (int i = 0; i < 4; i++)
#pragma unroll
                for (int j = 0; j < 4; j++) acc[i][j] += ra[i] * rb[j];
        }
        __syncthreads();
    }
#pragma unroll
    for (int i = 0; i < 4; i++) {
        int gr = row0 + ty * 4 + i;
        if (gr >= n) continue;
#pragma unroll
        for (int j = 0; j < 4; j++) {
            int gc = col0 + tx * 4 + j;
            float v = acc[i][j];
            if (bias1) v += bias1[gc];
            if (bias2) v += bias2[gc];
            C[(size_t)gr * M + gc] = v;
        }
    }
}

// a_s[n,h] = sum_c xh[n,h*C+c]*att_s[h*C+c]; same for a_d
template <int C>
__global__ void k_attn(const float* __restrict__ xh, const float* __restrict__ att_s,
                       const float* __restrict__ att_d, float* __restrict__ a_s,
                       float* __restrict__ a_d, int n) {
    int idx = blockIdx.x * blockDim.x + threadIdx.x;
    if (idx >= n * 4) return;
    int node = idx >> 2, h = idx & 3;
    const float* row = xh + (size_t)node * (4 * C) + h * C;
    float ss = 0.f, dd = 0.f;
#pragma unroll 4
    for (int c = 0; c < C; c++) {
        float v = row[c];
        ss += v * att_s[h * C + c];
        dd += v * att_d[h * C + c];
    }
    a_s[idx] = ss;
    a_d[idx] = dd;
}

// ---- CSR build ----
__global__ void k_hist(const int* __restrict__ edges, int E, int* __restrict__ deg) {
    int e = blockIdx.x * blockDim.x + threadIdx.x;
    if (e < E) atomicAdd(&deg[edges[E + e]], 1);
}

// in-place exclusive scan over rp[0..n) (single workgroup of 1024)
__global__ __launch_bounds__(1024) void k_scan(int* __restrict__ rp, int n) {
    __shared__ int wsum[16];
    __shared__ int s_carry;
    int lane = threadIdx.x & 63, wid = threadIdx.x >> 6;
    if (threadIdx.x == 0) s_carry = 0;
    __syncthreads();
    for (int base = 0; base < n; base += 1024) {
        int i = base + threadIdx.x;
        int v = (i < n) ? rp[i] : 0;
        int inc = v;
#pragma unroll
        for (int off = 1; off < 64; off <<= 1) {
            int t = __shfl_up(inc, off, 64);
            if (lane >= off) inc += t;
        }
        if (lane == 63) wsum[wid] = inc;
        __syncthreads();
        int carry = s_carry;
        __syncthreads();
        if (wid == 0) {
            int wv = (lane < 16) ? wsum[lane] : 0;
            int winc = wv;
#pragma unroll
            for (int off = 1; off < 16; off <<= 1) {
                int t = __shfl_up(winc, off, 64);
                if (lane >= off) winc += t;
            }
            if (lane < 16) wsum[lane] = winc - wv;  // exclusive wave offsets
            if (lane == 15) s_carry = carry + winc; // chunk total forward
        }
        __syncthreads();
        if (i < n) rp[i] = carry + wsum[wid] + (inc - v);  // exclusive prefix
        __syncthreads();  // protect wsum reuse next chunk
    }
}

// fill CSR; mutates rp so that afterwards rp[i] = end of row i
__global__ void k_fill(const int* __restrict__ edges, int E, int* __restrict__ rp,
                       int* __restrict__ csr) {
    int e = blockIdx.x * blockDim.x + threadIdx.x;
    if (e >= E) return;
    int d = edges[E + e];
    int pos = atomicAdd(&rp[d], 1);
    csr[pos] = edges[e];  // src
}

// One wave per dst node: per-head softmax over in-edges (+self-loop) and
// alpha-weighted gather-accumulate. FUSE: out = relu(agg + lin), else out = agg.
template <int HC, int C, bool FUSE>
__global__ __launch_bounds__(256) void k_node_agg(const int* __restrict__ rp,
                                                  const int* __restrict__ csr,
                                                  const float* __restrict__ a_s,
                                                  const float* __restrict__ a_d,
                                                  const float* __restrict__ xh,
                                                  const float* __restrict__ lin,
                                                  float* __restrict__ out, int n) {
    int node = (int)((blockIdx.x * blockDim.x + threadIdx.x) >> 6);
    if (node >= n) return;
    int lane = threadIdx.x & 63;
    constexpr int VC = HC / 64;  // 4 or 8
    int c0 = lane * VC;
    int h = c0 / C;
    int start = node ? rp[node - 1] : 0;  // post-fill trick: rp[i-1] = start of row i
    int end = rp[node];
    float ad = a_d[node * 4 + h];
    float sl = lrelu(a_s[node * 4 + h] + ad);  // self-loop logit
    float mx = sl;
    for (int e = start; e < end; e++) {
        int s = csr[e];
        mx = fmaxf(mx, lrelu(a_s[s * 4 + h] + ad));
    }
    float z = expf(sl - mx);
    float acc[VC];
    {
        const float4* xs = (const float4*)(xh + (size_t)node * HC + c0);
#pragma unroll
        for (int j = 0; j < VC / 4; j++) {
            float4 v = xs[j];
            acc[4 * j + 0] = z * v.x;
            acc[4 * j + 1] = z * v.y;
            acc[4 * j + 2] = z * v.z;
            acc[4 * j + 3] = z * v.w;
        }
    }
    for (int e = start; e < end; e++) {
        int s = csr[e];
        float w = expf(lrelu(a_s[s * 4 + h] + ad) - mx);
        z += w;
        const float4* xs = (const float4*)(xh + (size_t)s * HC + c0);
#pragma unroll
        for (int j = 0; j < VC / 4; j++) {
            float4 v = xs[j];
            acc[4 * j + 0] += w * v.x;
            acc[4 * j + 1] += w * v.y;
            acc[4 * j + 2] += w * v.z;
            acc[4 * j + 3] += w * v.w;
        }
    }
    float inv = 1.f / (z + 1e-16f);
    float4* op = (float4*)(out + (size_t)node * HC + c0);
    if (FUSE) {
        const float4* lp = (const float4*)(lin + (size_t)node * HC + c0);
#pragma unroll
        for (int j = 0; j < VC / 4; j++) {
            float4 l = lp[j];
            float4 r;
            r.x = fmaxf(acc[4 * j + 0] * inv + l.x, 0.f);
            r.y = fmaxf(acc[4 * j + 1] * inv + l.y, 0.f);
            r.z = fmaxf(acc[4 * j + 2] * inv + l.z, 0.f);
            r.w = fmaxf(acc[4 * j + 3] * inv + l.w, 0.f);
            op[j] = r;
        }
    } else {
#pragma unroll
        for (int j = 0; j < VC / 4; j++) {
            float4 r;
            r.x = acc[4 * j + 0] * inv;
            r.y = acc[4 * j + 1] * inv;
            r.z = acc[4 * j + 2] * inv;
            r.w = acc[4 * j + 3] * inv;
            op[j] = r;
        }
    }
}

// out3[n,c] = mean_h(agg[n,h,c]) + b3[c] + lin3[n,c]; scatter into pool[batch[n],c]
__global__ void k_combine3(const float* __restrict__ agg, const float* __restrict__ lin3,
                           const float* __restrict__ b3, const int* __restrict__ batch,
                           float* __restrict__ pool, float* __restrict__ cnt, int n) {
    int idx = blockIdx.x * blockDim.x + threadIdx.x;
    if (idx >= n * 128) return;
    int node = idx >> 7, c = idx & 127;
    const float* a = agg + (size_t)node * 512;
    float v = 0.25f * (a[c] + a[128 + c] + a[256 + c] + a[384 + c]) + b3[c] + lin3[idx];
    int g = batch[node];
    atomicAdd(&pool[g * 128 + c], v);
    if (c == 0) atomicAdd(&cnt[g], 1.0f);
}

__global__ void k_div(float* __restrict__ out, const float* __restrict__ cnt, int total) {
    int idx = blockIdx.x * blockDim.x + threadIdx.x;
    if (idx >= total) return;
    int g = idx >> 7;
    out[idx] /= fmaxf(cnt[g], 1.0f);
}

static inline int cdiv(int a, int b) { return (a + b - 1) / b; }

extern "C" void kernel_launch(void* const* d_in, const int* in_sizes, int n_in,
                              void* d_out, int out_size, void* d_ws, size_t ws_size,
                              hipStream_t stream) {
    const int* x_l = (const int*)d_in[0];
    const int* edge_l = (const int*)d_in[1];
    const int* batch_l = (const int*)d_in[2];
    const int* x_r = (const int*)d_in[3];
    const int* edge_r = (const int*)d_in[4];
    const int* batch_r = (const int*)d_in[5];
    const float* emb = (const float*)d_in[6];
    const float* W1 = (const float*)d_in[7];
    const float* as1 = (const float*)d_in[8];
    const float* ad1 = (const float*)d_in[9];
    const float* b1 = (const float*)d_in[10];
    const float* lw1 = (const float*)d_in[11];
    const float* lb1 = (const float*)d_in[12];
    const float* W2 = (const float*)d_in[13];
    const float* as2 = (const float*)d_in[14];
    const float* ad2 = (const float*)d_in[15];
    const float* b2 = (const float*)d_in[16];
    const float* lw2 = (const float*)d_in[17];
    const float* lb2 = (const float*)d_in[18];
    const float* W3 = (const float*)d_in[19];
    const float* as3 = (const float*)d_in[20];
    const float* ad3 = (const float*)d_in[21];
    const float* b3 = (const float*)d_in[22];
    const float* lw3 = (const float*)d_in[23];
    const float* lb3 = (const float*)d_in[24];

    const int n = in_sizes[0];       // 20000
    const int E = in_sizes[1] / 2;   // 320000

    float* P0 = (float*)d_ws;                 // [n,512] xh buffer
    float* P1 = P0 + (size_t)n * 512;         // [n,512] lin / agg
    float* P2 = P1 + (size_t)n * 512;         // [n,512] features
    float* L3 = P2 + (size_t)n * 512;         // [n,128] layer-3 skip
    float* a_s = L3 + (size_t)n * 128;        // [n,4]
    float* a_d = a_s + (size_t)n * 4;
    float* cnt = a_d + (size_t)n * 4;         // [2*G]
    int* rp = (int*)(cnt + 2 * GG);           // [n] degree -> prefix -> row-ends
    int* csr = rp + n;                        // [E] src ids sorted by dst

    hipMemsetAsync(d_out, 0, sizeof(float) * (size_t)out_size, stream);
    hipMemsetAsync(cnt, 0, sizeof(float) * 2 * GG, stream);

    const int TB = 256;
    dim3 blk(TB);

    for (int side = 0; side < 2; side++) {
        const int* xi = side ? x_r : x_l;
        const int* edges = side ? edge_r : edge_l;
        const int* batch = side ? batch_r : batch_l;
        float* pool = (float*)d_out + (size_t)side * GG * 128;
        float* cside = cnt + side * GG;

        // ---- CSR build (reused by all 3 layers) ----
        hipMemsetAsync(rp, 0, sizeof(int) * (size_t)n, stream);
        k_hist<<<cdiv(E, TB), blk, 0, stream>>>(edges, E, rp);
        k_scan<<<1, 1024, 0, stream>>>(rp, n);
        k_fill<<<cdiv(E, TB), blk, 0, stream>>>(edges, E, rp, csr);

        // embed -> P2 [n,128]
        k_embed<<<cdiv(n * 128, TB), blk, 0, stream>>>(xi, emb, P2, n);

        // ---- layer 1 (K=128, HC=256, C=64) ----
        k_gemm<<<dim3(cdiv(n, 64), 4), blk, 0, stream>>>(P2, W1, P0, n, 128, 256, nullptr, nullptr);
        k_gemm<<<dim3(cdiv(n, 64), 4), blk, 0, stream>>>(P2, lw1, P1, n, 128, 256, lb1, b1);
        k_attn<64><<<cdiv(n * 4, TB), blk, 0, stream>>>(P0, as1, ad1, a_s, a_d, n);
        k_node_agg<256, 64, true><<<cdiv(n * 64, TB), blk, 0, stream>>>(rp, csr, a_s, a_d, P0, P1, P1, n);

        // ---- layer 2 (K=256, HC=256, C=64) ----
        k_gemm<<<dim3(cdiv(n, 64), 4), blk, 0, stream>>>(P1, W2, P0, n, 256, 256, nullptr, nullptr);
        k_gemm<<<dim3(cdiv(n, 64), 4), blk, 0, stream>>>(P1, lw2, P2, n, 256, 256, lb2, b2);
        k_attn<64><<<cdiv(n * 4, TB), blk, 0, stream>>>(P0, as2, ad2, a_s, a_d, n);
        k_node_agg<256, 64, true><<<cdiv(n * 64, TB), blk, 0, stream>>>(rp, csr, a_s, a_d, P0, P2, P2, n);

        // ---- layer 3 (K=256, HC=512, C=128, concat=False) ----
        k_gemm<<<dim3(cdiv(n, 64), 8), blk, 0, stream>>>(P2, W3, P0, n, 256, 512, nullptr, nullptr);
        k_gemm<<<dim3(cdiv(n, 64), 2), blk, 0, stream>>>(P2, lw3, L3, n, 256, 128, lb3, nullptr);
        k_attn<128><<<cdiv(n * 4, TB), blk, 0, stream>>>(P0, as3, ad3, a_s, a_d, n);
        k_node_agg<512, 128, false><<<cdiv(n * 64, TB), blk, 0, stream>>>(rp, csr, a_s, a_d, P0, nullptr, P1, n);
        k_combine3<<<cdiv(n * 128, TB), blk, 0, stream>>>(P1, L3, b3, batch, pool, cside, n);
    }
    k_div<<<cdiv(2 * GG * 128, TB), blk, 0, stream>>>((float*)d_out, cnt, 2 * GG * 128);
}

// Round 3
// 1152.901 us; speedup vs baseline: 13.6200x; 1.4578x over previous
//
#include <hip/hip_runtime.h>

#define GG 256

typedef __bf16 bf16x8 __attribute__((ext_vector_type(8)));
typedef __bf16 bf16x4 __attribute__((ext_vector_type(4)));
typedef float floatx4 __attribute__((ext_vector_type(4)));

__device__ __forceinline__ float lrelu(float x) { return x > 0.f ? x : 0.2f * x; }

// e_bf[n,c] = bf16(emb[xi[n]*128 + c]); 16 threads/node, 8 ch each
__global__ void k_embed_bf(const int* __restrict__ xi, const float* __restrict__ emb,
                           __bf16* __restrict__ e, int n) {
    int t = blockIdx.x * blockDim.x + threadIdx.x;
    if (t >= n * 16) return;
    int node = t >> 4, c0 = (t & 15) * 8;
    const float4* src = (const float4*)(emb + ((size_t)xi[node] << 7) + c0);
    float4 v0 = src[0], v1 = src[1];
    bf16x8 o = {(__bf16)v0.x, (__bf16)v0.y, (__bf16)v0.z, (__bf16)v0.w,
                (__bf16)v1.x, (__bf16)v1.y, (__bf16)v1.z, (__bf16)v1.w};
    *(bf16x8*)(e + (size_t)node * 128 + c0) = o;
}

// Bt[m*K+k] = bf16(B[k*M+m])  (transpose + convert, tiny matrices)
__global__ void k_wt(const float* __restrict__ B, __bf16* __restrict__ Bt, int K, int M) {
    int idx = blockIdx.x * blockDim.x + threadIdx.x;
    if (idx >= K * M) return;
    int k = idx / M, m = idx - k * M;
    Bt[(size_t)m * K + k] = (__bf16)B[idx];
}

// C[n,M] = A[n,K] @ Bt[M,K]^T (+bias1)(+bias2); MFMA bf16, fp32 acc.
// 128x64 block tile, BK=64, 256 threads (4 waves, each 32 rows x 64 cols).
__global__ __launch_bounds__(256) void k_gemm_bf16(const __bf16* __restrict__ A,
                                                   const __bf16* __restrict__ Bt,
                                                   float* __restrict__ C,
                                                   int n, int K, int M,
                                                   const float* __restrict__ bias1,
                                                   const float* __restrict__ bias2) {
    __shared__ __bf16 As[128][72];  // 72: 16B-aligned row stride, start banks spread
    __shared__ __bf16 Bs[64][72];
    int tid = threadIdx.x;
    int wave = tid >> 6, lane = tid & 63;
    int row0 = blockIdx.x * 128, col0 = blockIdx.y * 64;
    floatx4 acc[2][4] = {};
    int lr = tid >> 3;          // 0..31
    int lk = (tid & 7) * 8;     // k elem offset
    for (int k0 = 0; k0 < K; k0 += 64) {
#pragma unroll
        for (int i = 0; i < 4; i++) {
            int r = lr + i * 32;
            int gr = row0 + r;
            bf16x8 v = {};
            if (gr < n) v = *(const bf16x8*)(A + (size_t)gr * K + k0 + lk);
            *(bf16x8*)&As[r][lk] = v;
        }
#pragma unroll
        for (int i = 0; i < 2; i++) {
            int r = lr + i * 32;
            bf16x8 v = *(const bf16x8*)(Bt + (size_t)(col0 + r) * K + k0 + lk);
            *(bf16x8*)&Bs[r][lk] = v;
        }
        __syncthreads();
#pragma unroll
        for (int ks = 0; ks < 2; ks++) {
            int ko = ks * 32 + (lane >> 4) * 8;
            bf16x8 af[2], bfr[4];
#pragma unroll
            for (int rt = 0; rt < 2; rt++)
                af[rt] = *(const bf16x8*)&As[wave * 32 + rt * 16 + (lane & 15)][ko];
#pragma unroll
            for (int ct = 0; ct < 4; ct++)
                bfr[ct] = *(const bf16x8*)&Bs[ct * 16 + (lane & 15)][ko];
#pragma unroll
            for (int rt = 0; rt < 2; rt++)
#pragma unroll
                for (int ct = 0; ct < 4; ct++)
                    acc[rt][ct] = __builtin_amdgcn_mfma_f32_16x16x32_bf16(
                        af[rt], bfr[ct], acc[rt][ct], 0, 0, 0);
        }
        __syncthreads();
    }
    // C/D layout: col = lane&15, row = (lane>>4)*4 + reg
    int crow = row0 + wave * 32 + ((lane >> 4) << 2);
    int ccol = col0 + (lane & 15);
#pragma unroll
    for (int rt = 0; rt < 2; rt++) {
#pragma unroll
        for (int r = 0; r < 4; r++) {
            int gr = crow + rt * 16 + r;
            if (gr >= n) continue;
#pragma unroll
            for (int ct = 0; ct < 4; ct++) {
                int gc = ccol + ct * 16;
                float v = acc[rt][ct][r];
                if (bias1) v += bias1[gc];
                if (bias2) v += bias2[gc];
                C[(size_t)gr * M + gc] = v;
            }
        }
    }
}

// a_s[n,h] = sum_c xh[n,h*C+c]*att_s[h*C+c]; same for a_d (float4 vectorized)
template <int C>
__global__ void k_attn(const float* __restrict__ xh, const float* __restrict__ att_s,
                       const float* __restrict__ att_d, float* __restrict__ a_s,
                       float* __restrict__ a_d, int n) {
    int idx = blockIdx.x * blockDim.x + threadIdx.x;
    if (idx >= n * 4) return;
    int node = idx >> 2, h = idx & 3;
    const float4* row = (const float4*)(xh + (size_t)node * (4 * C) + h * C);
    const float4* ws = (const float4*)(att_s + h * C);
    const float4* wd = (const float4*)(att_d + h * C);
    float ss = 0.f, dd = 0.f;
#pragma unroll
    for (int c = 0; c < C / 4; c++) {
        float4 v = row[c], s4 = ws[c], d4 = wd[c];
        ss += v.x * s4.x + v.y * s4.y + v.z * s4.z + v.w * s4.w;
        dd += v.x * d4.x + v.y * d4.y + v.z * d4.z + v.w * d4.w;
    }
    a_s[idx] = ss;
    a_d[idx] = dd;
}

// ---- CSR build ----
__global__ void k_hist(const int* __restrict__ edges, int E, int* __restrict__ deg) {
    int e = blockIdx.x * blockDim.x + threadIdx.x;
    if (e < E) atomicAdd(&deg[edges[E + e]], 1);
}

__global__ __launch_bounds__(1024) void k_scan(int* __restrict__ rp, int n) {
    __shared__ int wsum[16];
    __shared__ int s_carry;
    int lane = threadIdx.x & 63, wid = threadIdx.x >> 6;
    if (threadIdx.x == 0) s_carry = 0;
    __syncthreads();
    for (int base = 0; base < n; base += 1024) {
        int i = base + threadIdx.x;
        int v = (i < n) ? rp[i] : 0;
        int inc = v;
#pragma unroll
        for (int off = 1; off < 64; off <<= 1) {
            int t = __shfl_up(inc, off, 64);
            if (lane >= off) inc += t;
        }
        if (lane == 63) wsum[wid] = inc;
        __syncthreads();
        int carry = s_carry;
        __syncthreads();
        if (wid == 0) {
            int wv = (lane < 16) ? wsum[lane] : 0;
            int winc = wv;
#pragma unroll
            for (int off = 1; off < 16; off <<= 1) {
                int t = __shfl_up(winc, off, 64);
                if (lane >= off) winc += t;
            }
            if (lane < 16) wsum[lane] = winc - wv;
            if (lane == 15) s_carry = carry + winc;
        }
        __syncthreads();
        if (i < n) rp[i] = carry + wsum[wid] + (inc - v);
        __syncthreads();
    }
}

__global__ void k_fill(const int* __restrict__ edges, int E, int* __restrict__ rp,
                       int* __restrict__ csr) {
    int e = blockIdx.x * blockDim.x + threadIdx.x;
    if (e >= E) return;
    int d = edges[E + e];
    int pos = atomicAdd(&rp[d], 1);
    csr[pos] = edges[e];
}

// One wave per dst node: per-head softmax over in-edges (+self-loop), gather-acc.
// FUSE: out = relu(agg + lin) (+ bf16 copy for next layer's GEMM A); else out = agg.
template <int HC, int C, bool FUSE>
__global__ __launch_bounds__(256) void k_node_agg(const int* __restrict__ rp,
                                                  const int* __restrict__ csr,
                                                  const float* __restrict__ a_s,
                                                  const float* __restrict__ a_d,
                                                  const float* __restrict__ xh,
                                                  const float* __restrict__ lin,
                                                  float* __restrict__ out,
                                                  __bf16* __restrict__ out_bf, int n) {
    int node = (int)((blockIdx.x * blockDim.x + threadIdx.x) >> 6);
    if (node >= n) return;
    int lane = threadIdx.x & 63;
    constexpr int VC = HC / 64;
    int c0 = lane * VC;
    int h = c0 / C;
    int start = node ? rp[node - 1] : 0;
    int end = rp[node];
    float ad = a_d[node * 4 + h];
    float sl = lrelu(a_s[node * 4 + h] + ad);
    float mx = sl;
    for (int e = start; e < end; e++) {
        int s = csr[e];
        mx = fmaxf(mx, lrelu(a_s[s * 4 + h] + ad));
    }
    float z = expf(sl - mx);
    float acc[VC];
    {
        const float4* xs = (const float4*)(xh + (size_t)node * HC + c0);
#pragma unroll
        for (int j = 0; j < VC / 4; j++) {
            float4 v = xs[j];
            acc[4 * j + 0] = z * v.x;
            acc[4 * j + 1] = z * v.y;
            acc[4 * j + 2] = z * v.z;
            acc[4 * j + 3] = z * v.w;
        }
    }
    for (int e = start; e < end; e++) {
        int s = csr[e];
        float w = expf(lrelu(a_s[s * 4 + h] + ad) - mx);
        z += w;
        const float4* xs = (const float4*)(xh + (size_t)s * HC + c0);
#pragma unroll
        for (int j = 0; j < VC / 4; j++) {
            float4 v = xs[j];
            acc[4 * j + 0] += w * v.x;
            acc[4 * j + 1] += w * v.y;
            acc[4 * j + 2] += w * v.z;
            acc[4 * j + 3] += w * v.w;
        }
    }
    float inv = 1.f / (z + 1e-16f);
    float4* op = (float4*)(out + (size_t)node * HC + c0);
    if (FUSE) {
        const float4* lp = (const float4*)(lin + (size_t)node * HC + c0);
#pragma unroll
        for (int j = 0; j < VC / 4; j++) {
            float4 l = lp[j];
            float4 r;
            r.x = fmaxf(acc[4 * j + 0] * inv + l.x, 0.f);
            r.y = fmaxf(acc[4 * j + 1] * inv + l.y, 0.f);
            r.z = fmaxf(acc[4 * j + 2] * inv + l.z, 0.f);
            r.w = fmaxf(acc[4 * j + 3] * inv + l.w, 0.f);
            op[j] = r;
            bf16x4 rb = {(__bf16)r.x, (__bf16)r.y, (__bf16)r.z, (__bf16)r.w};
            *(bf16x4*)(out_bf + (size_t)node * HC + c0 + 4 * j) = rb;
        }
    } else {
#pragma unroll
        for (int j = 0; j < VC / 4; j++) {
            float4 r;
            r.x = acc[4 * j + 0] * inv;
            r.y = acc[4 * j + 1] * inv;
            r.z = acc[4 * j + 2] * inv;
            r.w = acc[4 * j + 3] * inv;
            op[j] = r;
        }
    }
}

__global__ void k_combine3(const float* __restrict__ agg, const float* __restrict__ lin3,
                           const float* __restrict__ b3, const int* __restrict__ batch,
                           float* __restrict__ pool, float* __restrict__ cnt, int n) {
    int idx = blockIdx.x * blockDim.x + threadIdx.x;
    if (idx >= n * 128) return;
    int node = idx >> 7, c = idx & 127;
    const float* a = agg + (size_t)node * 512;
    float v = 0.25f * (a[c] + a[128 + c] + a[256 + c] + a[384 + c]) + b3[c] + lin3[idx];
    int g = batch[node];
    atomicAdd(&pool[g * 128 + c], v);
    if (c == 0) atomicAdd(&cnt[g], 1.0f);
}

__global__ void k_div(float* __restrict__ out, const float* __restrict__ cnt, int total) {
    int idx = blockIdx.x * blockDim.x + threadIdx.x;
    if (idx >= total) return;
    int g = idx >> 7;
    out[idx] /= fmaxf(cnt[g], 1.0f);
}

static inline int cdiv(int a, int b) { return (a + b - 1) / b; }

extern "C" void kernel_launch(void* const* d_in, const int* in_sizes, int n_in,
                              void* d_out, int out_size, void* d_ws, size_t ws_size,
                              hipStream_t stream) {
    const int* x_l = (const int*)d_in[0];
    const int* edge_l = (const int*)d_in[1];
    const int* batch_l = (const int*)d_in[2];
    const int* x_r = (const int*)d_in[3];
    const int* edge_r = (const int*)d_in[4];
    const int* batch_r = (const int*)d_in[5];
    const float* emb = (const float*)d_in[6];
    const float* W1 = (const float*)d_in[7];
    const float* as1 = (const float*)d_in[8];
    const float* ad1 = (const float*)d_in[9];
    const float* b1 = (const float*)d_in[10];
    const float* lw1 = (const float*)d_in[11];
    const float* lb1 = (const float*)d_in[12];
    const float* W2 = (const float*)d_in[13];
    const float* as2 = (const float*)d_in[14];
    const float* ad2 = (const float*)d_in[15];
    const float* b2 = (const float*)d_in[16];
    const float* lw2 = (const float*)d_in[17];
    const float* lb2 = (const float*)d_in[18];
    const float* W3 = (const float*)d_in[19];
    const float* as3 = (const float*)d_in[20];
    const float* ad3 = (const float*)d_in[21];
    const float* b3 = (const float*)d_in[22];
    const float* lw3 = (const float*)d_in[23];
    const float* lb3 = (const float*)d_in[24];

    const int n = in_sizes[0];       // 20000
    const int E = in_sizes[1] / 2;   // 320000

    float* P0 = (float*)d_ws;                 // [n,512] xh
    float* P1 = P0 + (size_t)n * 512;         // [n,512] lin / agg
    float* P2 = P1 + (size_t)n * 512;         // [n,512] features
    float* L3 = P2 + (size_t)n * 512;         // [n,128] layer-3 skip
    float* a_s = L3 + (size_t)n * 128;
    float* a_d = a_s + (size_t)n * 4;
    float* cnt = a_d + (size_t)n * 4;         // [2*G]
    int* rp = (int*)(cnt + 2 * GG);           // [n]
    int* csr = rp + n;                        // [E]
    __bf16* Abf = (__bf16*)(csr + E);         // [n,256] bf16 GEMM-A (reused per layer)
    __bf16* W1t = Abf + (size_t)n * 256;      // transposed bf16 weights
    __bf16* l1t = W1t + 256 * 128;
    __bf16* W2t = l1t + 256 * 128;
    __bf16* l2t = W2t + 256 * 256;
    __bf16* W3t = l2t + 256 * 256;
    __bf16* l3t = W3t + 512 * 256;            // + 128*256

    hipMemsetAsync(d_out, 0, sizeof(float) * (size_t)out_size, stream);
    hipMemsetAsync(cnt, 0, sizeof(float) * 2 * GG, stream);

    const int TB = 256;
    dim3 blk(TB);

    // weight transpose+convert (shared by both sides)
    k_wt<<<cdiv(128 * 256, TB), blk, 0, stream>>>(W1, W1t, 128, 256);
    k_wt<<<cdiv(128 * 256, TB), blk, 0, stream>>>(lw1, l1t, 128, 256);
    k_wt<<<cdiv(256 * 256, TB), blk, 0, stream>>>(W2, W2t, 256, 256);
    k_wt<<<cdiv(256 * 256, TB), blk, 0, stream>>>(lw2, l2t, 256, 256);
    k_wt<<<cdiv(256 * 512, TB), blk, 0, stream>>>(W3, W3t, 256, 512);
    k_wt<<<cdiv(256 * 128, TB), blk, 0, stream>>>(lw3, l3t, 256, 128);

    for (int side = 0; side < 2; side++) {
        const int* xi = side ? x_r : x_l;
        const int* edges = side ? edge_r : edge_l;
        const int* batch = side ? batch_r : batch_l;
        float* pool = (float*)d_out + (size_t)side * GG * 128;
        float* cside = cnt + side * GG;

        // CSR build
        hipMemsetAsync(rp, 0, sizeof(int) * (size_t)n, stream);
        k_hist<<<cdiv(E, TB), blk, 0, stream>>>(edges, E, rp);
        k_scan<<<1, 1024, 0, stream>>>(rp, n);
        k_fill<<<cdiv(E, TB), blk, 0, stream>>>(edges, E, rp, csr);

        // embed -> Abf [n,128] bf16
        k_embed_bf<<<cdiv(n * 16, TB), blk, 0, stream>>>(xi, emb, Abf, n);

        // ---- layer 1 (K=128, HC=256, C=64) ----
        k_gemm_bf16<<<dim3(cdiv(n, 128), 4), blk, 0, stream>>>(Abf, W1t, P0, n, 128, 256, nullptr, nullptr);
        k_gemm_bf16<<<dim3(cdiv(n, 128), 4), blk, 0, stream>>>(Abf, l1t, P1, n, 128, 256, lb1, b1);
        k_attn<64><<<cdiv(n * 4, TB), blk, 0, stream>>>(P0, as1, ad1, a_s, a_d, n);
        k_node_agg<256, 64, true><<<cdiv(n * 64, TB), blk, 0, stream>>>(rp, csr, a_s, a_d, P0, P1, P1, Abf, n);

        // ---- layer 2 (K=256, HC=256, C=64) ----
        k_gemm_bf16<<<dim3(cdiv(n, 128), 4), blk, 0, stream>>>(Abf, W2t, P0, n, 256, 256, nullptr, nullptr);
        k_gemm_bf16<<<dim3(cdiv(n, 128), 4), blk, 0, stream>>>(Abf, l2t, P2, n, 256, 256, lb2, b2);
        k_attn<64><<<cdiv(n * 4, TB), blk, 0, stream>>>(P0, as2, ad2, a_s, a_d, n);
        k_node_agg<256, 64, true><<<cdiv(n * 64, TB), blk, 0, stream>>>(rp, csr, a_s, a_d, P0, P2, P2, Abf, n);

        // ---- layer 3 (K=256, HC=512, C=128, concat=False) ----
        k_gemm_bf16<<<dim3(cdiv(n, 128), 8), blk, 0, stream>>>(Abf, W3t, P0, n, 256, 512, nullptr, nullptr);
        k_gemm_bf16<<<dim3(cdiv(n, 128), 2), blk, 0, stream>>>(Abf, l3t, L3, n, 256, 128, lb3, nullptr);
        k_attn<128><<<cdiv(n * 4, TB), blk, 0, stream>>>(P0, as3, ad3, a_s, a_d, n);
        k_node_agg<512, 128, false><<<cdiv(n * 64, TB), blk, 0, stream>>>(rp, csr, a_s, a_d, P0, nullptr, P1, nullptr, n);
        k_combine3<<<cdiv(n * 128, TB), blk, 0, stream>>>(P1, L3, b3, batch, pool, cside, n);
    }
    k_div<<<cdiv(2 * GG * 128, TB), blk, 0, stream>>>((float*)d_out, cnt, 2 * GG * 128);
}

// Round 4
// 1023.088 us; speedup vs baseline: 15.3481x; 1.1269x over previous
//
#include <hip/hip_runtime.h>

#define GG 256

typedef __bf16 bf16x8 __attribute__((ext_vector_type(8)));
typedef __bf16 bf16x4 __attribute__((ext_vector_type(4)));
typedef float floatx4 __attribute__((ext_vector_type(4)));

__device__ __forceinline__ float lrelu(float x) { return x > 0.f ? x : 0.2f * x; }

// e_bf[n,c] = bf16(emb[xi[n]*128 + c]); 16 threads/node, 8 ch each
__global__ void k_embed_bf(const int* __restrict__ xi, const float* __restrict__ emb,
                           __bf16* __restrict__ e, int n) {
    int t = blockIdx.x * blockDim.x + threadIdx.x;
    if (t >= n * 16) return;
    int node = t >> 4, c0 = (t & 15) * 8;
    const float4* src = (const float4*)(emb + ((size_t)xi[node] << 7) + c0);
    float4 v0 = src[0], v1 = src[1];
    bf16x8 o = {(__bf16)v0.x, (__bf16)v0.y, (__bf16)v0.z, (__bf16)v0.w,
                (__bf16)v1.x, (__bf16)v1.y, (__bf16)v1.z, (__bf16)v1.w};
    *(bf16x8*)(e + (size_t)node * 128 + c0) = o;
}

// Bt[m*K+k] = bf16(B[k*M+m])  (transpose + convert, tiny matrices)
__global__ void k_wt(const float* __restrict__ B, __bf16* __restrict__ Bt, int K, int M) {
    int idx = blockIdx.x * blockDim.x + threadIdx.x;
    if (idx >= K * M) return;
    int k = idx / M, m = idx - k * M;
    Bt[(size_t)m * K + k] = (__bf16)B[idx];
}

// Fused GEMM: A[n,K](bf16) @ Bt[Mtot,K]^T. Columns < Msplit -> xh (bf16, ld=ldx).
// Columns >= Msplit -> lin (fp32, ld=ldl) + bias1 (+bias2).
// 128x64 tile, BK=64, 256 threads (4 waves x 2x4 16x16x32 MFMA frags).
__global__ __launch_bounds__(256) void k_gemm_fused(const __bf16* __restrict__ A,
                                                    const __bf16* __restrict__ Bt,
                                                    int n, int K, int Msplit,
                                                    __bf16* __restrict__ xh, int ldx,
                                                    float* __restrict__ lin, int ldl,
                                                    const float* __restrict__ bias1,
                                                    const float* __restrict__ bias2) {
    __shared__ __bf16 As[128][72];
    __shared__ __bf16 Bs[64][72];
    int tid = threadIdx.x;
    int wave = tid >> 6, lane = tid & 63;
    int row0 = blockIdx.x * 128, col0 = blockIdx.y * 64;
    floatx4 acc[2][4] = {};
    int lr = tid >> 3;          // 0..31
    int lk = (tid & 7) * 8;     // k elem offset
    for (int k0 = 0; k0 < K; k0 += 64) {
#pragma unroll
        for (int i = 0; i < 4; i++) {
            int r = lr + i * 32;
            int gr = row0 + r;
            bf16x8 v = {};
            if (gr < n) v = *(const bf16x8*)(A + (size_t)gr * K + k0 + lk);
            *(bf16x8*)&As[r][lk] = v;
        }
#pragma unroll
        for (int i = 0; i < 2; i++) {
            int r = lr + i * 32;
            bf16x8 v = *(const bf16x8*)(Bt + (size_t)(col0 + r) * K + k0 + lk);
            *(bf16x8*)&Bs[r][lk] = v;
        }
        __syncthreads();
#pragma unroll
        for (int ks = 0; ks < 2; ks++) {
            int ko = ks * 32 + (lane >> 4) * 8;
            bf16x8 af[2], bfr[4];
#pragma unroll
            for (int rt = 0; rt < 2; rt++)
                af[rt] = *(const bf16x8*)&As[wave * 32 + rt * 16 + (lane & 15)][ko];
#pragma unroll
            for (int ct = 0; ct < 4; ct++)
                bfr[ct] = *(const bf16x8*)&Bs[ct * 16 + (lane & 15)][ko];
#pragma unroll
            for (int rt = 0; rt < 2; rt++)
#pragma unroll
                for (int ct = 0; ct < 4; ct++)
                    acc[rt][ct] = __builtin_amdgcn_mfma_f32_16x16x32_bf16(
                        af[rt], bfr[ct], acc[rt][ct], 0, 0, 0);
        }
        __syncthreads();
    }
    // C/D layout: col = lane&15, row = (lane>>4)*4 + reg
    int crow = row0 + wave * 32 + ((lane >> 4) << 2);
    int ccol = col0 + (lane & 15);
    if (col0 < Msplit) {  // xh part (block-uniform branch)
#pragma unroll
        for (int rt = 0; rt < 2; rt++)
#pragma unroll
            for (int r = 0; r < 4; r++) {
                int gr = crow + rt * 16 + r;
                if (gr >= n) continue;
#pragma unroll
                for (int ct = 0; ct < 4; ct++)
                    xh[(size_t)gr * ldx + ccol + ct * 16] = (__bf16)acc[rt][ct][r];
            }
    } else {  // lin part
#pragma unroll
        for (int rt = 0; rt < 2; rt++)
#pragma unroll
            for (int r = 0; r < 4; r++) {
                int gr = crow + rt * 16 + r;
                if (gr >= n) continue;
#pragma unroll
                for (int ct = 0; ct < 4; ct++) {
                    int c2 = ccol + ct * 16 - Msplit;
                    float v = acc[rt][ct][r] + bias1[c2];
                    if (bias2) v += bias2[c2];
                    lin[(size_t)gr * ldl + c2] = v;
                }
            }
    }
}

// a_s[n,h] = sum_c xh[n,h*C+c]*att_s[h*C+c]; same for a_d (bf16 xh)
template <int C>
__global__ void k_attn(const __bf16* __restrict__ xh, int ld,
                       const float* __restrict__ att_s, const float* __restrict__ att_d,
                       float* __restrict__ a_s, float* __restrict__ a_d, int n) {
    int idx = blockIdx.x * blockDim.x + threadIdx.x;
    if (idx >= n * 4) return;
    int node = idx >> 2, h = idx & 3;
    const __bf16* row = xh + (size_t)node * ld + h * C;
    const float* ws = att_s + h * C;
    const float* wd = att_d + h * C;
    float ss = 0.f, dd = 0.f;
#pragma unroll
    for (int c0 = 0; c0 < C; c0 += 8) {
        bf16x8 v8 = *(const bf16x8*)(row + c0);
#pragma unroll
        for (int j = 0; j < 8; j++) {
            float v = (float)v8[j];
            ss += v * ws[c0 + j];
            dd += v * wd[c0 + j];
        }
    }
    a_s[idx] = ss;
    a_d[idx] = dd;
}

// ---- CSR build ----
__global__ void k_hist(const int* __restrict__ edges, int E, int* __restrict__ deg) {
    int e = blockIdx.x * blockDim.x + threadIdx.x;
    if (e < E) atomicAdd(&deg[edges[E + e]], 1);
}

__global__ __launch_bounds__(1024) void k_scan(int* __restrict__ rp, int n) {
    __shared__ int wsum[16];
    __shared__ int s_carry;
    int lane = threadIdx.x & 63, wid = threadIdx.x >> 6;
    if (threadIdx.x == 0) s_carry = 0;
    __syncthreads();
    for (int base = 0; base < n; base += 1024) {
        int i = base + threadIdx.x;
        int v = (i < n) ? rp[i] : 0;
        int inc = v;
#pragma unroll
        for (int off = 1; off < 64; off <<= 1) {
            int t = __shfl_up(inc, off, 64);
            if (lane >= off) inc += t;
        }
        if (lane == 63) wsum[wid] = inc;
        __syncthreads();
        int carry = s_carry;
        __syncthreads();
        if (wid == 0) {
            int wv = (lane < 16) ? wsum[lane] : 0;
            int winc = wv;
#pragma unroll
            for (int off = 1; off < 16; off <<= 1) {
                int t = __shfl_up(winc, off, 64);
                if (lane >= off) winc += t;
            }
            if (lane < 16) wsum[lane] = winc - wv;
            if (lane == 15) s_carry = carry + winc;
        }
        __syncthreads();
        if (i < n) rp[i] = carry + wsum[wid] + (inc - v);
        __syncthreads();
    }
}

__global__ void k_fill(const int* __restrict__ edges, int E, int* __restrict__ rp,
                       int* __restrict__ csr) {
    int e = blockIdx.x * blockDim.x + threadIdx.x;
    if (e >= E) return;
    int d = edges[E + e];
    int pos = atomicAdd(&rp[d], 1);
    csr[pos] = edges[e];
}

// One wave per dst node; bf16 gathers, fp32 accumulate.
// FUSE: out_bf = bf16(relu(agg + lin)); else out_f = agg (fp32).
template <int HC, int C, bool FUSE>
__global__ __launch_bounds__(256) void k_node_agg(const int* __restrict__ rp,
                                                  const int* __restrict__ csr,
                                                  const float* __restrict__ a_s,
                                                  const float* __restrict__ a_d,
                                                  const __bf16* __restrict__ xh,
                                                  const float* __restrict__ lin,
                                                  float* __restrict__ out_f,
                                                  __bf16* __restrict__ out_bf, int n) {
    constexpr int VC = HC / 64;  // 4 or 8
    typedef __bf16 bvec __attribute__((ext_vector_type(VC)));
    int node = (int)((blockIdx.x * blockDim.x + threadIdx.x) >> 6);
    if (node >= n) return;
    int lane = threadIdx.x & 63;
    int c0 = lane * VC;
    int h = c0 / C;
    int start = node ? rp[node - 1] : 0;
    int end = rp[node];
    float ad = a_d[node * 4 + h];
    float sl = lrelu(a_s[node * 4 + h] + ad);
    float mx = sl;
    for (int e = start; e < end; e++) {
        int s = csr[e];
        mx = fmaxf(mx, lrelu(a_s[s * 4 + h] + ad));
    }
    float z = expf(sl - mx);
    float acc[VC];
    {
        bvec v = *(const bvec*)(xh + (size_t)node * HC + c0);
#pragma unroll
        for (int j = 0; j < VC; j++) acc[j] = z * (float)v[j];
    }
    for (int e = start; e < end; e++) {
        int s = csr[e];
        float w = expf(lrelu(a_s[s * 4 + h] + ad) - mx);
        z += w;
        bvec v = *(const bvec*)(xh + (size_t)s * HC + c0);
#pragma unroll
        for (int j = 0; j < VC; j++) acc[j] += w * (float)v[j];
    }
    float inv = 1.f / (z + 1e-16f);
    if (FUSE) {
        float l[VC];
        const float4* lp = (const float4*)(lin + (size_t)node * HC + c0);
#pragma unroll
        for (int jj = 0; jj < VC / 4; jj++) {
            float4 t = lp[jj];
            l[4 * jj + 0] = t.x; l[4 * jj + 1] = t.y;
            l[4 * jj + 2] = t.z; l[4 * jj + 3] = t.w;
        }
        bvec r;
#pragma unroll
        for (int j = 0; j < VC; j++)
            r[j] = (__bf16)fmaxf(acc[j] * inv + l[j], 0.f);
        *(bvec*)(out_bf + (size_t)node * HC + c0) = r;
    } else {
        float4* op = (float4*)(out_f + (size_t)node * HC + c0);
#pragma unroll
        for (int jj = 0; jj < VC / 4; jj++) {
            float4 r;
            r.x = acc[4 * jj + 0] * inv;
            r.y = acc[4 * jj + 1] * inv;
            r.z = acc[4 * jj + 2] * inv;
            r.w = acc[4 * jj + 3] * inv;
            op[jj] = r;
        }
    }
}

__global__ void k_combine3(const float* __restrict__ agg, const float* __restrict__ lin3,
                           const float* __restrict__ b3, const int* __restrict__ batch,
                           float* __restrict__ pool, float* __restrict__ cnt, int n) {
    int idx = blockIdx.x * blockDim.x + threadIdx.x;
    if (idx >= n * 128) return;
    int node = idx >> 7, c = idx & 127;
    const float* a = agg + (size_t)node * 512;
    float v = 0.25f * (a[c] + a[128 + c] + a[256 + c] + a[384 + c]) + b3[c] + lin3[idx];
    int g = batch[node];
    atomicAdd(&pool[g * 128 + c], v);
    if (c == 0) atomicAdd(&cnt[g], 1.0f);
}

__global__ void k_div(float* __restrict__ out, const float* __restrict__ cnt, int total) {
    int idx = blockIdx.x * blockDim.x + threadIdx.x;
    if (idx >= total) return;
    int g = idx >> 7;
    out[idx] /= fmaxf(cnt[g], 1.0f);
}

static inline int cdiv(int a, int b) { return (a + b - 1) / b; }

extern "C" void kernel_launch(void* const* d_in, const int* in_sizes, int n_in,
                              void* d_out, int out_size, void* d_ws, size_t ws_size,
                              hipStream_t stream) {
    const int* x_l = (const int*)d_in[0];
    const int* edge_l = (const int*)d_in[1];
    const int* batch_l = (const int*)d_in[2];
    const int* x_r = (const int*)d_in[3];
    const int* edge_r = (const int*)d_in[4];
    const int* batch_r = (const int*)d_in[5];
    const float* emb = (const float*)d_in[6];
    const float* W1 = (const float*)d_in[7];
    const float* as1 = (const float*)d_in[8];
    const float* ad1 = (const float*)d_in[9];
    const float* b1 = (const float*)d_in[10];
    const float* lw1 = (const float*)d_in[11];
    const float* lb1 = (const float*)d_in[12];
    const float* W2 = (const float*)d_in[13];
    const float* as2 = (const float*)d_in[14];
    const float* ad2 = (const float*)d_in[15];
    const float* b2 = (const float*)d_in[16];
    const float* lw2 = (const float*)d_in[17];
    const float* lb2 = (const float*)d_in[18];
    const float* W3 = (const float*)d_in[19];
    const float* as3 = (const float*)d_in[20];
    const float* ad3 = (const float*)d_in[21];
    const float* b3 = (const float*)d_in[22];
    const float* lw3 = (const float*)d_in[23];
    const float* lb3 = (const float*)d_in[24];

    const int n = in_sizes[0];       // 20000
    const int E = in_sizes[1] / 2;   // 320000

    float* P1 = (float*)d_ws;                  // [n,512] layer-3 agg
    float* LIN = P1 + (size_t)n * 512;         // [n,256] lin skip L1/L2
    float* L3 = LIN + (size_t)n * 256;         // [n,128] layer-3 skip
    float* a_s = L3 + (size_t)n * 128;         // [n,4]
    float* a_d = a_s + (size_t)n * 4;
    float* cnt = a_d + (size_t)n * 4;          // [2*G]
    int* rp = (int*)(cnt + 2 * GG);            // [n]
    int* csr = rp + n;                         // [E]
    __bf16* Xbf = (__bf16*)(csr + E);          // [n,512] xh (bf16)
    __bf16* Abf = Xbf + (size_t)n * 512;       // [n,256] GEMM A
    __bf16* W1t = Abf + (size_t)n * 256;       // combined transposed weights
    __bf16* l1t = W1t + 256 * 128;             // -> [512][128]
    __bf16* W2t = l1t + 256 * 128;
    __bf16* l2t = W2t + 256 * 256;             // -> [512][256]
    __bf16* W3t = l2t + 256 * 256;
    __bf16* l3t = W3t + 512 * 256;             // -> [640][256]

    hipMemsetAsync(d_out, 0, sizeof(float) * (size_t)out_size, stream);
    hipMemsetAsync(cnt, 0, sizeof(float) * 2 * GG, stream);

    const int TB = 256;
    dim3 blk(TB);

    // weight transpose+convert (shared by both sides)
    k_wt<<<cdiv(128 * 256, TB), blk, 0, stream>>>(W1, W1t, 128, 256);
    k_wt<<<cdiv(128 * 256, TB), blk, 0, stream>>>(lw1, l1t, 128, 256);
    k_wt<<<cdiv(256 * 256, TB), blk, 0, stream>>>(W2, W2t, 256, 256);
    k_wt<<<cdiv(256 * 256, TB), blk, 0, stream>>>(lw2, l2t, 256, 256);
    k_wt<<<cdiv(256 * 512, TB), blk, 0, stream>>>(W3, W3t, 256, 512);
    k_wt<<<cdiv(256 * 128, TB), blk, 0, stream>>>(lw3, l3t, 256, 128);

    for (int side = 0; side < 2; side++) {
        const int* xi = side ? x_r : x_l;
        const int* edges = side ? edge_r : edge_l;
        const int* batch = side ? batch_r : batch_l;
        float* pool = (float*)d_out + (size_t)side * GG * 128;
        float* cside = cnt + side * GG;

        // CSR build
        hipMemsetAsync(rp, 0, sizeof(int) * (size_t)n, stream);
        k_hist<<<cdiv(E, TB), blk, 0, stream>>>(edges, E, rp);
        k_scan<<<1, 1024, 0, stream>>>(rp, n);
        k_fill<<<cdiv(E, TB), blk, 0, stream>>>(edges, E, rp, csr);

        // embed -> Abf [n,128] bf16
        k_embed_bf<<<cdiv(n * 16, TB), blk, 0, stream>>>(xi, emb, Abf, n);

        // ---- layer 1 (K=128, Mtot=512, split 256) ----
        k_gemm_fused<<<dim3(cdiv(n, 128), 8), blk, 0, stream>>>(
            Abf, W1t, n, 128, 256, Xbf, 256, LIN, 256, lb1, b1);
        k_attn<64><<<cdiv(n * 4, TB), blk, 0, stream>>>(Xbf, 256, as1, ad1, a_s, a_d, n);
        k_node_agg<256, 64, true><<<cdiv(n * 64, TB), blk, 0, stream>>>(
            rp, csr, a_s, a_d, Xbf, LIN, nullptr, Abf, n);

        // ---- layer 2 (K=256, Mtot=512, split 256) ----
        k_gemm_fused<<<dim3(cdiv(n, 128), 8), blk, 0, stream>>>(
            Abf, W2t, n, 256, 256, Xbf, 256, LIN, 256, lb2, b2);
        k_attn<64><<<cdiv(n * 4, TB), blk, 0, stream>>>(Xbf, 256, as2, ad2, a_s, a_d, n);
        k_node_agg<256, 64, true><<<cdiv(n * 64, TB), blk, 0, stream>>>(
            rp, csr, a_s, a_d, Xbf, LIN, nullptr, Abf, n);

        // ---- layer 3 (K=256, Mtot=640, split 512) ----
        k_gemm_fused<<<dim3(cdiv(n, 128), 10), blk, 0, stream>>>(
            Abf, W3t, n, 256, 512, Xbf, 512, L3, 128, lb3, nullptr);
        k_attn<128><<<cdiv(n * 4, TB), blk, 0, stream>>>(Xbf, 512, as3, ad3, a_s, a_d, n);
        k_node_agg<512, 128, false><<<cdiv(n * 64, TB), blk, 0, stream>>>(
            rp, csr, a_s, a_d, Xbf, nullptr, P1, nullptr, n);
        k_combine3<<<cdiv(n * 128, TB), blk, 0, stream>>>(P1, L3, b3, batch, pool, cside, n);
    }
    k_div<<<cdiv(2 * GG * 128, TB), blk, 0, stream>>>((float*)d_out, cnt, 2 * GG * 128);
}

// Round 5
// 787.175 us; speedup vs baseline: 19.9479x; 1.2997x over previous
//
#include <hip/hip_runtime.h>

#define GG 256

typedef __bf16 bf16x8 __attribute__((ext_vector_type(8)));
typedef float floatx4 __attribute__((ext_vector_type(4)));
typedef float f32x2 __attribute__((ext_vector_type(2)));

__device__ __forceinline__ float lrelu(float x) { return x > 0.f ? x : 0.2f * x; }

// e_bf[n,c] = bf16(emb[xi[n]*128 + c]); 16 threads/node, 8 ch each
__global__ void k_embed_bf(const int* __restrict__ xi, const float* __restrict__ emb,
                           __bf16* __restrict__ e, int n) {
    int t = blockIdx.x * blockDim.x + threadIdx.x;
    if (t >= n * 16) return;
    int node = t >> 4, c0 = (t & 15) * 8;
    const float4* src = (const float4*)(emb + ((size_t)xi[node] << 7) + c0);
    float4 v0 = src[0], v1 = src[1];
    bf16x8 o = {(__bf16)v0.x, (__bf16)v0.y, (__bf16)v0.z, (__bf16)v0.w,
                (__bf16)v1.x, (__bf16)v1.y, (__bf16)v1.z, (__bf16)v1.w};
    *(bf16x8*)(e + (size_t)node * 128 + c0) = o;
}

// Bt[m*K+k] = bf16(B[k*M+m])
__global__ void k_wt(const float* __restrict__ B, __bf16* __restrict__ Bt, int K, int M) {
    int idx = blockIdx.x * blockDim.x + threadIdx.x;
    if (idx >= K * M) return;
    int k = idx / M, m = idx - k * M;
    Bt[(size_t)m * K + k] = (__bf16)B[idx];
}

// Fused GEMM: A[n,K](bf16) @ Bt[Mtot,K]^T. cols < Msplit -> xh (bf16, ldx);
// cols >= Msplit -> lin (fp32, ldl) + bias1 (+bias2).
__global__ __launch_bounds__(256) void k_gemm_fused(const __bf16* __restrict__ A,
                                                    const __bf16* __restrict__ Bt,
                                                    int n, int K, int Msplit,
                                                    __bf16* __restrict__ xh, int ldx,
                                                    float* __restrict__ lin, int ldl,
                                                    const float* __restrict__ bias1,
                                                    const float* __restrict__ bias2) {
    __shared__ __bf16 As[128][72];
    __shared__ __bf16 Bs[64][72];
    int tid = threadIdx.x;
    int wave = tid >> 6, lane = tid & 63;
    int row0 = blockIdx.x * 128, col0 = blockIdx.y * 64;
    floatx4 acc[2][4] = {};
    int lr = tid >> 3;
    int lk = (tid & 7) * 8;
    for (int k0 = 0; k0 < K; k0 += 64) {
#pragma unroll
        for (int i = 0; i < 4; i++) {
            int r = lr + i * 32;
            int gr = row0 + r;
            bf16x8 v = {};
            if (gr < n) v = *(const bf16x8*)(A + (size_t)gr * K + k0 + lk);
            *(bf16x8*)&As[r][lk] = v;
        }
#pragma unroll
        for (int i = 0; i < 2; i++) {
            int r = lr + i * 32;
            bf16x8 v = *(const bf16x8*)(Bt + (size_t)(col0 + r) * K + k0 + lk);
            *(bf16x8*)&Bs[r][lk] = v;
        }
        __syncthreads();
#pragma unroll
        for (int ks = 0; ks < 2; ks++) {
            int ko = ks * 32 + (lane >> 4) * 8;
            bf16x8 af[2], bfr[4];
#pragma unroll
            for (int rt = 0; rt < 2; rt++)
                af[rt] = *(const bf16x8*)&As[wave * 32 + rt * 16 + (lane & 15)][ko];
#pragma unroll
            for (int ct = 0; ct < 4; ct++)
                bfr[ct] = *(const bf16x8*)&Bs[ct * 16 + (lane & 15)][ko];
#pragma unroll
            for (int rt = 0; rt < 2; rt++)
#pragma unroll
                for (int ct = 0; ct < 4; ct++)
                    acc[rt][ct] = __builtin_amdgcn_mfma_f32_16x16x32_bf16(
                        af[rt], bfr[ct], acc[rt][ct], 0, 0, 0);
        }
        __syncthreads();
    }
    int crow = row0 + wave * 32 + ((lane >> 4) << 2);
    int ccol = col0 + (lane & 15);
    if (col0 < Msplit) {
#pragma unroll
        for (int rt = 0; rt < 2; rt++)
#pragma unroll
            for (int r = 0; r < 4; r++) {
                int gr = crow + rt * 16 + r;
                if (gr >= n) continue;
#pragma unroll
                for (int ct = 0; ct < 4; ct++)
                    xh[(size_t)gr * ldx + ccol + ct * 16] = (__bf16)acc[rt][ct][r];
            }
    } else {
#pragma unroll
        for (int rt = 0; rt < 2; rt++)
#pragma unroll
            for (int r = 0; r < 4; r++) {
                int gr = crow + rt * 16 + r;
                if (gr >= n) continue;
#pragma unroll
                for (int ct = 0; ct < 4; ct++) {
                    int c2 = ccol + ct * 16 - Msplit;
                    float v = acc[rt][ct][r] + bias1[c2];
                    if (bias2) v += bias2[c2];
                    lin[(size_t)gr * ldl + c2] = v;
                }
            }
    }
}

// a_s[n,h] = sum_c xh[n,h*C+c]*att_s[h*C+c]; same for a_d (bf16 xh)
template <int C>
__global__ void k_attn(const __bf16* __restrict__ xh, int ld,
                       const float* __restrict__ att_s, const float* __restrict__ att_d,
                       float* __restrict__ a_s, float* __restrict__ a_d, int n) {
    int idx = blockIdx.x * blockDim.x + threadIdx.x;
    if (idx >= n * 4) return;
    int node = idx >> 2, h = idx & 3;
    const __bf16* row = xh + (size_t)node * ld + h * C;
    const float* ws = att_s + h * C;
    const float* wd = att_d + h * C;
    float ss = 0.f, dd = 0.f;
#pragma unroll
    for (int c0 = 0; c0 < C; c0 += 8) {
        bf16x8 v8 = *(const bf16x8*)(row + c0);
#pragma unroll
        for (int j = 0; j < 8; j++) {
            float v = (float)v8[j];
            ss += v * ws[c0 + j];
            dd += v * wd[c0 + j];
        }
    }
    a_s[idx] = ss;
    a_d[idx] = dd;
}

// ---- CSR build ----
__global__ void k_hist(const int* __restrict__ edges, int E, int* __restrict__ deg) {
    int e = blockIdx.x * blockDim.x + threadIdx.x;
    if (e < E) atomicAdd(&deg[edges[E + e]], 1);
}

__global__ __launch_bounds__(1024) void k_scan(int* __restrict__ rp, int n) {
    __shared__ int wsum[16];
    __shared__ int s_carry;
    int lane = threadIdx.x & 63, wid = threadIdx.x >> 6;
    if (threadIdx.x == 0) s_carry = 0;
    __syncthreads();
    for (int base = 0; base < n; base += 1024) {
        int i = base + threadIdx.x;
        int v = (i < n) ? rp[i] : 0;
        int inc = v;
#pragma unroll
        for (int off = 1; off < 64; off <<= 1) {
            int t = __shfl_up(inc, off, 64);
            if (lane >= off) inc += t;
        }
        if (lane == 63) wsum[wid] = inc;
        __syncthreads();
        int carry = s_carry;
        __syncthreads();
        if (wid == 0) {
            int wv = (lane < 16) ? wsum[lane] : 0;
            int winc = wv;
#pragma unroll
            for (int off = 1; off < 16; off <<= 1) {
                int t = __shfl_up(winc, off, 64);
                if (lane >= off) winc += t;
            }
            if (lane < 16) wsum[lane] = winc - wv;
            if (lane == 15) s_carry = carry + winc;
        }
        __syncthreads();
        if (i < n) rp[i] = carry + wsum[wid] + (inc - v);
        __syncthreads();
    }
}

__global__ void k_fill(const int* __restrict__ edges, int E, int* __restrict__ rp,
                       int* __restrict__ csr) {
    int e = blockIdx.x * blockDim.x + threadIdx.x;
    if (e >= E) return;
    int d = edges[E + e];
    int pos = atomicAdd(&rp[d], 1);
    csr[pos] = edges[e];
}

// graph boundaries from sorted batch: gs[g] = lower_bound(batch, g), g in [0,G]
__global__ void k_gbound(const int* __restrict__ batch, int n, int* __restrict__ gs) {
    int g = blockIdx.x * blockDim.x + threadIdx.x;
    if (g > GG) return;
    int lo = 0, hi = n;
    while (lo < hi) {
        int mid = (lo + hi) >> 1;
        if (batch[mid] < g) lo = mid + 1; else hi = mid;
    }
    gs[g] = lo;
}

// Layers 1/2 aggregation: 2 nodes/wave (32 lanes x 8 bf16 ch each), no max pass.
// out_bf = bf16(relu(agg/z + lin))
__global__ __launch_bounds__(256) void k_agg12(const int* __restrict__ rp,
                                               const int* __restrict__ csr,
                                               const float* __restrict__ a_s,
                                               const float* __restrict__ a_d,
                                               const __bf16* __restrict__ xh,
                                               const float* __restrict__ lin,
                                               __bf16* __restrict__ out_bf, int n) {
    int wv = (int)((blockIdx.x * blockDim.x + threadIdx.x) >> 6);
    int lane = threadIdx.x & 63;
    int sub = lane >> 5, sl = lane & 31;
    int node = wv * 2 + sub;
    if (node >= n) return;
    int sbase = lane & 32;
    int c0 = sl * 8;          // 8 bf16 ch per lane
    int h = sl >> 3;          // c0/64
    int start = node ? rp[node - 1] : 0;
    int end = rp[node];
    float ad = a_d[node * 4 + h];
    float z = __expf(lrelu(a_s[node * 4 + h] + ad));  // self-loop
    float acc[8];
    {
        bf16x8 v = *(const bf16x8*)(xh + (size_t)node * 256 + c0);
#pragma unroll
        for (int j = 0; j < 8; j++) acc[j] = z * (float)v[j];
    }
    for (int eb = start; eb < end; eb += 32) {
        int myE = eb + sl;
        int mySrc = (myE < end) ? csr[myE] : 0;
        int cnt = min(32, end - eb);
        for (int j = 0; j < cnt; j++) {
            int s = __shfl(mySrc, sbase + j, 64);
            float w = __expf(lrelu(a_s[s * 4 + h] + ad));
            z += w;
            bf16x8 v = *(const bf16x8*)(xh + (size_t)s * 256 + c0);
#pragma unroll
            for (int q = 0; q < 8; q++) acc[q] += w * (float)v[q];
        }
    }
    float inv = 1.f / (z + 1e-16f);
    const float4* lp = (const float4*)(lin + (size_t)node * 256 + c0);
    float4 l0 = lp[0], l1 = lp[1];
    float lf[8] = {l0.x, l0.y, l0.z, l0.w, l1.x, l1.y, l1.z, l1.w};
    bf16x8 r;
#pragma unroll
    for (int j = 0; j < 8; j++)
        r[j] = (__bf16)fmaxf(acc[j] * inv + lf[j], 0.f);
    *(bf16x8*)(out_bf + (size_t)node * 256 + c0) = r;
}

// bf16 -> fp8 e4m3 (HW cvt), 8 elems/thread
__global__ void k_cvt8(const __bf16* __restrict__ src, unsigned int* __restrict__ dst,
                       int total8) {
    int t = blockIdx.x * blockDim.x + threadIdx.x;
    if (t >= total8) return;
    bf16x8 v = *(const bf16x8*)(src + (size_t)t * 8);
    int p0 = __builtin_amdgcn_cvt_pk_fp8_f32((float)v[0], (float)v[1], 0, false);
    p0 = __builtin_amdgcn_cvt_pk_fp8_f32((float)v[2], (float)v[3], p0, true);
    int p1 = __builtin_amdgcn_cvt_pk_fp8_f32((float)v[4], (float)v[5], 0, false);
    p1 = __builtin_amdgcn_cvt_pk_fp8_f32((float)v[6], (float)v[7], p1, true);
    ((uint2*)dst)[t] = make_uint2((unsigned int)p0, (unsigned int)p1);
}

__device__ __forceinline__ void dec4(unsigned int u, float* f) {
    f32x2 a = __builtin_amdgcn_cvt_pk_f32_fp8(u, false);
    f32x2 b = __builtin_amdgcn_cvt_pk_f32_fp8(u, true);
    f[0] = a[0]; f[1] = a[1]; f[2] = b[0]; f[3] = b[1];
}

// Layer-3 aggregation (HC=512, C=128) on fp8 rows; 2 nodes/wave (32 lanes x 16 ch);
// fused head-mean via shfl_xor -> mean[n,128] fp32.
__global__ __launch_bounds__(256) void k_agg3(const int* __restrict__ rp,
                                              const int* __restrict__ csr,
                                              const float* __restrict__ a_s,
                                              const float* __restrict__ a_d,
                                              const unsigned int* __restrict__ x8,  // [n,128] uints
                                              float* __restrict__ mean, int n) {
    int wv = (int)((blockIdx.x * blockDim.x + threadIdx.x) >> 6);
    int lane = threadIdx.x & 63;
    int sub = lane >> 5, sl = lane & 31;
    int node = wv * 2 + sub;
    if (node >= n) return;
    int sbase = lane & 32;
    int h = sl >> 3;          // 16 ch per lane, c0 = sl*16, h = c0/128
    int start = node ? rp[node - 1] : 0;
    int end = rp[node];
    float ad = a_d[node * 4 + h];
    float z = __expf(lrelu(a_s[node * 4 + h] + ad));
    float acc[16];
    {
        uint4 u = *(const uint4*)(x8 + (size_t)node * 128 + sl * 4);
        float f[16];
        dec4(u.x, f); dec4(u.y, f + 4); dec4(u.z, f + 8); dec4(u.w, f + 12);
#pragma unroll
        for (int j = 0; j < 16; j++) acc[j] = z * f[j];
    }
    for (int eb = start; eb < end; eb += 32) {
        int myE = eb + sl;
        int mySrc = (myE < end) ? csr[myE] : 0;
        int cnt = min(32, end - eb);
        for (int j = 0; j < cnt; j++) {
            int s = __shfl(mySrc, sbase + j, 64);
            float w = __expf(lrelu(a_s[s * 4 + h] + ad));
            z += w;
            uint4 u = *(const uint4*)(x8 + (size_t)s * 128 + sl * 4);
            float f[16];
            dec4(u.x, f); dec4(u.y, f + 4); dec4(u.z, f + 8); dec4(u.w, f + 12);
#pragma unroll
            for (int q = 0; q < 16; q++) acc[q] += w * f[q];
        }
    }
    float scale = 0.25f / (z + 1e-16f);  // alpha-normalize (per-head) + head-mean /4
#pragma unroll
    for (int j = 0; j < 16; j++) {
        float v = acc[j] * scale;
        v += __shfl_xor(v, 8, 64);
        v += __shfl_xor(v, 16, 64);
        acc[j] = v;
    }
    if ((sl & 24) == 0) {  // sl < 8: holds channels sl*16..sl*16+15
        float4* op = (float4*)(mean + (size_t)node * 128 + sl * 16);
#pragma unroll
        for (int q = 0; q < 4; q++) {
            float4 o = {acc[4 * q], acc[4 * q + 1], acc[4 * q + 2], acc[4 * q + 3]};
            op[q] = o;
        }
    }
}

// per-graph mean pool (no atomics): out[g,c] = sum_i(mean+lin3)/cnt + b3
__global__ __launch_bounds__(128) void k_pool(const float* __restrict__ mean,
                                              const float* __restrict__ lin3,
                                              const float* __restrict__ b3,
                                              const int* __restrict__ gs,
                                              float* __restrict__ out) {
    int g = blockIdx.x, c = threadIdx.x;
    int s = gs[g], e = gs[g + 1];
    float acc = 0.f;
    for (int i = s; i < e; i++)
        acc += mean[(size_t)i * 128 + c] + lin3[(size_t)i * 128 + c];
    int cnt = e - s;
    out[(size_t)g * 128 + c] = cnt > 0 ? acc / (float)cnt + b3[c] : 0.f;
}

static inline int cdiv(int a, int b) { return (a + b - 1) / b; }

extern "C" void kernel_launch(void* const* d_in, const int* in_sizes, int n_in,
                              void* d_out, int out_size, void* d_ws, size_t ws_size,
                              hipStream_t stream) {
    const int* x_l = (const int*)d_in[0];
    const int* edge_l = (const int*)d_in[1];
    const int* batch_l = (const int*)d_in[2];
    const int* x_r = (const int*)d_in[3];
    const int* edge_r = (const int*)d_in[4];
    const int* batch_r = (const int*)d_in[5];
    const float* emb = (const float*)d_in[6];
    const float* W1 = (const float*)d_in[7];
    const float* as1 = (const float*)d_in[8];
    const float* ad1 = (const float*)d_in[9];
    const float* b1 = (const float*)d_in[10];
    const float* lw1 = (const float*)d_in[11];
    const float* lb1 = (const float*)d_in[12];
    const float* W2 = (const float*)d_in[13];
    const float* as2 = (const float*)d_in[14];
    const float* ad2 = (const float*)d_in[15];
    const float* b2 = (const float*)d_in[16];
    const float* lw2 = (const float*)d_in[17];
    const float* lb2 = (const float*)d_in[18];
    const float* W3 = (const float*)d_in[19];
    const float* as3 = (const float*)d_in[20];
    const float* ad3 = (const float*)d_in[21];
    const float* b3 = (const float*)d_in[22];
    const float* lw3 = (const float*)d_in[23];
    const float* lb3 = (const float*)d_in[24];

    const int n = in_sizes[0];       // 20000
    const int E = in_sizes[1] / 2;   // 320000

    float* MEAN = (float*)d_ws;                // [n,128]
    float* LIN = MEAN + (size_t)n * 128;       // [n,256]
    float* L3 = LIN + (size_t)n * 256;         // [n,128]
    float* a_s = L3 + (size_t)n * 128;         // [n,4]
    float* a_d = a_s + (size_t)n * 4;
    int* rp = (int*)(a_d + (size_t)n * 4);     // [n]
    int* csr = rp + n;                         // [E]
    int* gs = csr + E;                         // [G+1]
    __bf16* Xbf = (__bf16*)(gs + GG + 1);      // [n,512]
    __bf16* Abf = Xbf + (size_t)n * 512;       // [n,256]
    unsigned int* X8 = (unsigned int*)(Abf + (size_t)n * 256);  // [n,128] uints (fp8)
    __bf16* W1t = (__bf16*)(X8 + (size_t)n * 128);
    __bf16* l1t = W1t + 256 * 128;
    __bf16* W2t = l1t + 256 * 128;
    __bf16* l2t = W2t + 256 * 256;
    __bf16* W3t = l2t + 256 * 256;
    __bf16* l3t = W3t + 512 * 256;

    const int TB = 256;
    dim3 blk(TB);

    k_wt<<<cdiv(128 * 256, TB), blk, 0, stream>>>(W1, W1t, 128, 256);
    k_wt<<<cdiv(128 * 256, TB), blk, 0, stream>>>(lw1, l1t, 128, 256);
    k_wt<<<cdiv(256 * 256, TB), blk, 0, stream>>>(W2, W2t, 256, 256);
    k_wt<<<cdiv(256 * 256, TB), blk, 0, stream>>>(lw2, l2t, 256, 256);
    k_wt<<<cdiv(256 * 512, TB), blk, 0, stream>>>(W3, W3t, 256, 512);
    k_wt<<<cdiv(256 * 128, TB), blk, 0, stream>>>(lw3, l3t, 256, 128);

    for (int side = 0; side < 2; side++) {
        const int* xi = side ? x_r : x_l;
        const int* edges = side ? edge_r : edge_l;
        const int* batch = side ? batch_r : batch_l;
        float* pool = (float*)d_out + (size_t)side * GG * 128;

        // CSR + graph bounds
        hipMemsetAsync(rp, 0, sizeof(int) * (size_t)n, stream);
        k_hist<<<cdiv(E, TB), blk, 0, stream>>>(edges, E, rp);
        k_scan<<<1, 1024, 0, stream>>>(rp, n);
        k_fill<<<cdiv(E, TB), blk, 0, stream>>>(edges, E, rp, csr);
        k_gbound<<<1, 512, 0, stream>>>(batch, n, gs);

        // embed -> Abf [n,128]
        k_embed_bf<<<cdiv(n * 16, TB), blk, 0, stream>>>(xi, emb, Abf, n);

        // ---- layer 1 ----
        k_gemm_fused<<<dim3(cdiv(n, 128), 8), blk, 0, stream>>>(
            Abf, W1t, n, 128, 256, Xbf, 256, LIN, 256, lb1, b1);
        k_attn<64><<<cdiv(n * 4, TB), blk, 0, stream>>>(Xbf, 256, as1, ad1, a_s, a_d, n);
        k_agg12<<<cdiv(n, 8), blk, 0, stream>>>(rp, csr, a_s, a_d, Xbf, LIN, Abf, n);

        // ---- layer 2 ----
        k_gemm_fused<<<dim3(cdiv(n, 128), 8), blk, 0, stream>>>(
            Abf, W2t, n, 256, 256, Xbf, 256, LIN, 256, lb2, b2);
        k_attn<64><<<cdiv(n * 4, TB), blk, 0, stream>>>(Xbf, 256, as2, ad2, a_s, a_d, n);
        k_agg12<<<cdiv(n, 8), blk, 0, stream>>>(rp, csr, a_s, a_d, Xbf, LIN, Abf, n);

        // ---- layer 3 ----
        k_gemm_fused<<<dim3(cdiv(n, 128), 10), blk, 0, stream>>>(
            Abf, W3t, n, 256, 512, Xbf, 512, L3, 128, lb3, nullptr);
        k_attn<128><<<cdiv(n * 4, TB), blk, 0, stream>>>(Xbf, 512, as3, ad3, a_s, a_d, n);
        k_cvt8<<<cdiv(n * 64, TB), blk, 0, stream>>>(Xbf, X8, n * 64);
        k_agg3<<<cdiv(n, 8), blk, 0, stream>>>(rp, csr, a_s, a_d, X8, MEAN, n);
        k_pool<<<GG, 128, 0, stream>>>(MEAN, L3, b3, gs, pool);
    }
}